// Round 8
// baseline (498.651 us; speedup 1.0000x reference)
//
#include <hip/hip_runtime.h>
#include <hip/hip_bf16.h>

#define NEG_SLOPE 0.2f
#define BN_EPS 1e-5f

typedef __attribute__((ext_vector_type(8))) short bf16x8;
typedef __attribute__((ext_vector_type(4))) float f32x4;

__device__ __forceinline__ float bf2f(unsigned short u) {
    union { unsigned int i; float f; } x;
    x.i = ((unsigned int)u) << 16;
    return x.f;
}
__device__ __forceinline__ unsigned short f2bf(float f) {
    __hip_bfloat16 b = __float2bfloat16(f);
    return *reinterpret_cast<unsigned short*>(&b);
}
__device__ __forceinline__ float lrelu(float v) {
    return v > 0.f ? v : NEG_SLOPE * v;
}
__device__ __forceinline__ void gload_lds16(const void* g, void* l) {
    __builtin_amdgcn_global_load_lds(
        (const __attribute__((address_space(1))) unsigned int*)(g),
        (__attribute__((address_space(3))) unsigned int*)(l),
        16, 0, 0);
}

// ---------------------------------------------------------------- CSR build
__global__ __launch_bounds__(256) void count_kernel(const int* __restrict__ dstl,
                                                    int E, int N, int* __restrict__ counts) {
    int i = blockIdx.x * 256 + threadIdx.x;
    if (i < E + N) {
        int d = (i < E) ? dstl[i] : (i - E);
        atomicAdd(&counts[d], 1);
    }
}

__device__ __forceinline__ int block_scan_incl(int v, int t) {
    int lane = t & 63, w = t >> 6;
    int sv = v;
    #pragma unroll
    for (int off = 1; off < 64; off <<= 1) {
        int u = __shfl_up(sv, off);
        if (lane >= off) sv += u;
    }
    __shared__ int ws[4];
    if (lane == 63) ws[w] = sv;
    __syncthreads();
    if (t == 0) {
        int a = 0;
        #pragma unroll
        for (int k = 0; k < 4; k++) { int x = ws[k]; ws[k] = a; a += x; }
    }
    __syncthreads();
    return sv + ws[w];
}

__global__ __launch_bounds__(256) void scan1(const int* __restrict__ counts,
                                             int* __restrict__ tmp,
                                             int* __restrict__ bsums, int n) {
    int t = threadIdx.x, i = blockIdx.x * 256 + t;
    int v = (i < n) ? counts[i] : 0;
    int incl = block_scan_incl(v, t);
    if (i < n) tmp[i] = incl;
    if (t == 255) bsums[blockIdx.x] = incl;
}

__global__ __launch_bounds__(256) void scan2(int* __restrict__ bsums, int nb) {
    int t = threadIdx.x;
    int v = (t < nb) ? bsums[t] : 0;
    int incl = block_scan_incl(v, t);
    if (t < nb) bsums[t] = incl - v;
}

__global__ __launch_bounds__(256) void scan3(const int* __restrict__ tmp,
                                             const int* __restrict__ bsums,
                                             const int* __restrict__ counts,
                                             int* __restrict__ indptr,
                                             int* __restrict__ cursor, int n) {
    int i = blockIdx.x * 256 + threadIdx.x;
    if (i < n) {
        int incl = tmp[i] + bsums[i >> 8];
        indptr[i + 1] = incl;
        cursor[i] = incl - counts[i];
        if (i == 0) indptr[0] = 0;
    }
}

__global__ __launch_bounds__(256) void fill_kernel(const int* __restrict__ srcl,
                                                   const int* __restrict__ dstl,
                                                   int E, int N,
                                                   int* __restrict__ cursor,
                                                   int* __restrict__ esrc) {
    int i = blockIdx.x * 256 + threadIdx.x;
    if (i < E + N) {
        int s, d;
        if (i < E) { s = srcl[i]; d = dstl[i]; }
        else       { s = d = i - E; }
        int slot = atomicAdd(&cursor[d], 1);
        esrc[slot] = s;
    }
}

// ---------------------------------------------------------------- prep: x->bf16 + all weight transposes
__global__ __launch_bounds__(256) void prep_all(const float* __restrict__ x,
                                                unsigned short* __restrict__ xb, int n4x,
                                                const float* __restrict__ W1,
                                                const float* __restrict__ Ws1,
                                                const float* __restrict__ W2,
                                                const float* __restrict__ Ws2,
                                                const float* __restrict__ W3,
                                                unsigned short* __restrict__ Wcat1,
                                                unsigned short* __restrict__ Wcat2,
                                                unsigned short* __restrict__ W3t) {
    int i = blockIdx.x * 256 + threadIdx.x;
    if (i < n4x) {
        float4 v = reinterpret_cast<const float4*>(x)[i];
        ushort4 o;
        o.x = f2bf(v.x); o.y = f2bf(v.y); o.z = f2bf(v.z); o.w = f2bf(v.w);
        reinterpret_cast<ushort4*>(xb)[i] = o;
        return;
    }
    int j = i - n4x;
    if (j < 32768) {                       // W1^T: 256 rows x 128
        int m = j >> 7, k = j & 127;
        Wcat1[j] = f2bf(W1[k * 256 + m]);
    } else if (j < 65536) {                // Ws1^T: rows 256..511
        int q = j - 32768; int m = q >> 7, k = q & 127;
        Wcat1[32768 + q] = f2bf(Ws1[k * 256 + m]);
    } else if (j < 131072) {               // W2^T: 256 rows x 256
        int q = j - 65536; int m = q >> 8, k = q & 255;
        Wcat2[q] = f2bf(W2[k * 256 + m]);
    } else if (j < 139264) {               // Ws2^T: rows 256..287
        int q = j - 131072; int m = q >> 8, k = q & 255;
        Wcat2[65536 + q] = f2bf(Ws2[k * 32 + m]);
    } else if (j < 147456) {               // W3^T: 32 rows x 256
        int q = j - 139264; int m = q >> 8, k = q & 255;
        W3t[q] = f2bf(W3[k * 32 + m]);
    }
}

// ---------------------------------------------------------------- tiled MFMA GEMM
// C[M x NCtot] = A[M x K](bf16) @ B, Bt[NCtot x K] = B^T (bf16).
// 128x128 tile, BK=32, double-buffered LDS via global_load_lds(16B).
// Epilogue (all bf16): col < split -> outBf (no bias); col >= split -> outSk + biasSk.
__global__ __launch_bounds__(256) void gemm_tile(const unsigned short* __restrict__ A,
                                                 const unsigned short* __restrict__ Bt,
                                                 unsigned short* __restrict__ outBf,
                                                 unsigned short* __restrict__ outSk,
                                                 const float* __restrict__ biasSk,
                                                 int M, int K, int NCtot, int split,
                                                 int ldBf, int ldSk) {
    __shared__ __align__(16) char smem[2][2][8192];
    int t = threadIdx.x;
    int w = t >> 6, lane = t & 63;
    int l16 = lane & 15, quad = lane >> 4;
    int warp_r = w >> 1, warp_c = w & 1;
    int rowBase = blockIdx.y * 128;
    int colBase = blockIdx.x * 128;

    int row_l = t & 127;
    int jchunk = t >> 7;
    int arow_st = rowBase + row_l; if (arow_st >= M) arow_st = M - 1;
    int bcol_st = colBase + row_l; if (bcol_st >= NCtot) bcol_st = NCtot - 1;
    const unsigned short* aRow = A + (size_t)arow_st * K;
    const unsigned short* bRow = Bt + (size_t)bcol_st * K;

    f32x4 acc[4][4];
    #pragma unroll
    for (int i = 0; i < 4; i++)
        #pragma unroll
        for (int j = 0; j < 4; j++) acc[i][j] = (f32x4){0.f, 0.f, 0.f, 0.f};

    auto stage = [&](int buf, int k0) {
        #pragma unroll
        for (int j = 0; j < 2; j++) {
            int chunk = j * 2 + jchunk;
            gload_lds16(aRow + k0 + chunk * 8, &smem[buf][0][(size_t)j * 4096 + (size_t)t * 16]);
            gload_lds16(bRow + k0 + chunk * 8, &smem[buf][1][(size_t)j * 4096 + (size_t)t * 16]);
        }
    };

    stage(0, 0);
    __syncthreads();
    int niter = K >> 5;
    for (int it = 0; it < niter; ++it) {
        if (it + 1 < niter) stage((it + 1) & 1, (it + 1) << 5);
        const char* Ab = &smem[it & 1][0][0];
        const char* Bb = &smem[it & 1][1][0];
        bf16x8 a[4], b[4];
        #pragma unroll
        for (int i = 0; i < 4; i++)
            a[i] = *reinterpret_cast<const bf16x8*>(Ab + quad * 2048 + (warp_r * 64 + i * 16 + l16) * 16);
        #pragma unroll
        for (int j = 0; j < 4; j++)
            b[j] = *reinterpret_cast<const bf16x8*>(Bb + quad * 2048 + (warp_c * 64 + j * 16 + l16) * 16);
        #pragma unroll
        for (int i = 0; i < 4; i++)
            #pragma unroll
            for (int j = 0; j < 4; j++)
                acc[i][j] = __builtin_amdgcn_mfma_f32_16x16x32_bf16(a[i], b[j], acc[i][j], 0, 0, 0);
        __syncthreads();
    }

    #pragma unroll
    for (int i = 0; i < 4; i++) {
        #pragma unroll
        for (int r = 0; r < 4; r++) {
            int row = rowBase + warp_r * 64 + i * 16 + quad * 4 + r;
            if (row >= M) continue;
            #pragma unroll
            for (int j = 0; j < 4; j++) {
                int c = colBase + warp_c * 64 + j * 16 + l16;
                if (c >= NCtot) continue;
                float v = acc[i][j][r];
                if (c < split) outBf[(size_t)row * ldBf + c] = f2bf(v);
                else           outSk[(size_t)row * ldSk + (c - split)] = f2bf(v + biasSk[c - split]);
            }
        }
    }
}

// ---------------------------------------------------------------- alpha (H=8,C=32), wave/node
__global__ __launch_bounds__(256) void alpha256(const unsigned short* __restrict__ h,
                                                const float* __restrict__ a_s,
                                                const float* __restrict__ a_d,
                                                float* __restrict__ as_out,
                                                float* __restrict__ ad_out, int N) {
    int t = threadIdx.x;
    int n = blockIdx.x * 4 + (t >> 6);
    if (n >= N) return;
    int lane = t & 63, lane4 = lane * 4;
    ushort4 hv = *reinterpret_cast<const ushort4*>(&h[(size_t)n * 256 + lane4]);
    float4 sv = *reinterpret_cast<const float4*>(&a_s[lane4]);
    float4 dv = *reinterpret_cast<const float4*>(&a_d[lane4]);
    float h0 = bf2f(hv.x), h1 = bf2f(hv.y), h2 = bf2f(hv.z), h3 = bf2f(hv.w);
    float va = h0 * sv.x + h1 * sv.y + h2 * sv.z + h3 * sv.w;
    float vd = h0 * dv.x + h1 * dv.y + h2 * dv.z + h3 * dv.w;
    #pragma unroll
    for (int off = 1; off < 8; off <<= 1) {
        va += __shfl_xor(va, off);
        vd += __shfl_xor(vd, off);
    }
    if ((lane & 7) == 0) {
        as_out[n * 8 + (lane >> 3)] = va;
        ad_out[n * 8 + (lane >> 3)] = vd;
    }
}

// ---------------------------------------------------------------- alpha (H=1,C=32), 8 nodes/wave
__global__ __launch_bounds__(256) void alpha32(const unsigned short* __restrict__ h,
                                               const float* __restrict__ a_s,
                                               const float* __restrict__ a_d,
                                               float* __restrict__ as_out,
                                               float* __restrict__ ad_out, int N) {
    int t = threadIdx.x;
    int lane = t & 63;
    int n = blockIdx.x * 32 + (t >> 6) * 8 + (lane >> 3);
    int c4 = (lane & 7) * 4;
    if (n >= N) return;
    ushort4 hv = *reinterpret_cast<const ushort4*>(&h[(size_t)n * 32 + c4]);
    float4 sv = *reinterpret_cast<const float4*>(&a_s[c4]);
    float4 dv = *reinterpret_cast<const float4*>(&a_d[c4]);
    float h0 = bf2f(hv.x), h1 = bf2f(hv.y), h2 = bf2f(hv.z), h3 = bf2f(hv.w);
    float va = h0 * sv.x + h1 * sv.y + h2 * sv.z + h3 * sv.w;
    float vd = h0 * dv.x + h1 * dv.y + h2 * dv.z + h3 * dv.w;
    #pragma unroll
    for (int off = 1; off < 8; off <<= 1) {
        va += __shfl_xor(va, off);
        vd += __shfl_xor(vd, off);
    }
    if ((lane & 7) == 0) {
        as_out[n] = va;
        ad_out[n] = vd;
    }
}

// ---------------------------------------------------------------- aggregation H=8,C=32
// One wave per node, single pass, pipelined weight chain, skip in bf16.
template <int MODE>
__global__ __launch_bounds__(256) void agg256(const unsigned short* __restrict__ hfeat,
                                              const float* __restrict__ as,
                                              const float* __restrict__ ad,
                                              const int* __restrict__ indptr,
                                              const int* __restrict__ esrc,
                                              const float* __restrict__ bias,
                                              const float* __restrict__ bn_g,
                                              const float* __restrict__ bn_b,
                                              const float* __restrict__ bn_m,
                                              const float* __restrict__ bn_v,
                                              const unsigned short* __restrict__ skip,
                                              unsigned short* __restrict__ out, int N) {
    int t = threadIdx.x;
    int n = blockIdx.x * 4 + (t >> 6);
    if (n >= N) return;
    int lane = t & 63;
    int e_sub = lane >> 3, h_sub = lane & 7;
    int ch_head = lane >> 3;
    int lane4 = lane * 4;
    int start = indptr[n], end = indptr[n + 1];
    int cnt = end - start;

    float adh = ad[n * 8 + h_sub];

    float4 acc = make_float4(0.f, 0.f, 0.f, 0.f);
    float sm = 0.f;
    int nfull = cnt & ~7;
    int i0 = start;
    int s_l = 0; float w8 = 0.f;
    if (nfull) {
        s_l = esrc[i0 + e_sub];
        w8 = __expf(lrelu(as[s_l * 8 + h_sub] + adh));
    }
    while (i0 < start + nfull) {
        int s_cur = s_l;
        float w_cur = w8;
        i0 += 8;
        if (i0 < start + nfull) {
            s_l = esrc[i0 + e_sub];
            w8 = __expf(lrelu(as[s_l * 8 + h_sub] + adh));
        }
        sm += w_cur;
        ushort4 hv[8];
        #pragma unroll
        for (int e = 0; e < 8; e++) {
            int se = __shfl(s_cur, e * 8);
            hv[e] = *reinterpret_cast<const ushort4*>(&hfeat[(size_t)se * 256 + lane4]);
        }
        #pragma unroll
        for (int e = 0; e < 8; e++) {
            float we = __shfl(w_cur, e * 8 + ch_head);
            acc.x = fmaf(we, bf2f(hv[e].x), acc.x);
            acc.y = fmaf(we, bf2f(hv[e].y), acc.y);
            acc.z = fmaf(we, bf2f(hv[e].z), acc.z);
            acc.w = fmaf(we, bf2f(hv[e].w), acc.w);
        }
    }
    int rem = cnt - nfull;
    if (rem) {
        int idx = i0 + e_sub;
        int s_r = esrc[idx < end ? idx : end - 1];
        float w_r = (idx < end) ? __expf(lrelu(as[s_r * 8 + h_sub] + adh)) : 0.f;
        sm += w_r;
        #pragma unroll
        for (int e = 0; e < 8; e++) {
            if (e < rem) {
                int se = __shfl(s_r, e * 8);
                float we = __shfl(w_r, e * 8 + ch_head);
                ushort4 hv = *reinterpret_cast<const ushort4*>(&hfeat[(size_t)se * 256 + lane4]);
                acc.x = fmaf(we, bf2f(hv.x), acc.x);
                acc.y = fmaf(we, bf2f(hv.y), acc.y);
                acc.z = fmaf(we, bf2f(hv.z), acc.z);
                acc.w = fmaf(we, bf2f(hv.w), acc.w);
            }
        }
    }
    #pragma unroll
    for (int off = 8; off < 64; off <<= 1) sm += __shfl_xor(sm, off);
    float il = 1.f / (sm + 1e-16f);
    float il_c = __shfl(il, ch_head);

    float4 bv  = *reinterpret_cast<const float4*>(&bias[lane4]);
    float4 gv  = *reinterpret_cast<const float4*>(&bn_g[lane4]);
    float4 bbv = *reinterpret_cast<const float4*>(&bn_b[lane4]);
    float4 mv  = *reinterpret_cast<const float4*>(&bn_m[lane4]);
    float4 vv  = *reinterpret_cast<const float4*>(&bn_v[lane4]);
    float o[4] = {acc.x * il_c + bv.x, acc.y * il_c + bv.y,
                  acc.z * il_c + bv.z, acc.w * il_c + bv.w};
    float g[4] = {gv.x, gv.y, gv.z, gv.w}, bb[4] = {bbv.x, bbv.y, bbv.z, bbv.w};
    float m[4] = {mv.x, mv.y, mv.z, mv.w}, vr[4] = {vv.x, vv.y, vv.z, vv.w};
    float sk[4] = {0.f, 0.f, 0.f, 0.f};
    if (MODE == 1) {
        ushort4 s4 = *reinterpret_cast<const ushort4*>(&skip[(size_t)n * 256 + lane4]);
        sk[0] = bf2f(s4.x); sk[1] = bf2f(s4.y); sk[2] = bf2f(s4.z); sk[3] = bf2f(s4.w);
    }
    ushort4 res;
    unsigned short* rp = &res.x;
    #pragma unroll
    for (int j = 0; j < 4; j++) {
        float val = (o[j] - m[j]) * rsqrtf(vr[j] + BN_EPS) * g[j] + bb[j];
        val = val > 0.f ? val : (__expf(val) - 1.f);
        val += sk[j];
        rp[j] = f2bf(val);
    }
    *reinterpret_cast<ushort4*>(&out[(size_t)n * 256 + lane4]) = res;
}

// ---------------------------------------------------------------- aggregation H=1,C=32
__global__ __launch_bounds__(256) void agg32(const unsigned short* __restrict__ h3,
                                             const float* __restrict__ as,
                                             const float* __restrict__ ad,
                                             const int* __restrict__ indptr,
                                             const int* __restrict__ esrc,
                                             const float* __restrict__ b3,
                                             const unsigned short* __restrict__ xs,
                                             float* __restrict__ out, int N) {
    int t = threadIdx.x;
    int n = blockIdx.x * 4 + (t >> 6);
    if (n >= N) return;
    int lane = t & 63;
    int e_sub = lane >> 3, c4 = (lane & 7) * 4;
    int start = indptr[n], end = indptr[n + 1];
    float adn = ad[n];

    float4 acc = make_float4(0.f, 0.f, 0.f, 0.f);
    float sm = 0.f;
    int i0 = start;
    for (; i0 + 16 <= end; i0 += 16) {
        int sA = esrc[i0 + e_sub];
        int sB = esrc[i0 + 8 + e_sub];
        float wA = __expf(lrelu(as[sA] + adn));
        float wB = __expf(lrelu(as[sB] + adn));
        sm += wA + wB;
        ushort4 hA = *reinterpret_cast<const ushort4*>(&h3[(size_t)sA * 32 + c4]);
        ushort4 hB = *reinterpret_cast<const ushort4*>(&h3[(size_t)sB * 32 + c4]);
        acc.x = fmaf(wA, bf2f(hA.x), acc.x); acc.y = fmaf(wA, bf2f(hA.y), acc.y);
        acc.z = fmaf(wA, bf2f(hA.z), acc.z); acc.w = fmaf(wA, bf2f(hA.w), acc.w);
        acc.x = fmaf(wB, bf2f(hB.x), acc.x); acc.y = fmaf(wB, bf2f(hB.y), acc.y);
        acc.z = fmaf(wB, bf2f(hB.z), acc.z); acc.w = fmaf(wB, bf2f(hB.w), acc.w);
    }
    for (; i0 < end; i0 += 8) {
        int idx = i0 + e_sub;
        bool valid = idx < end;
        if (valid) {
            int s = esrc[idx];
            float w = __expf(lrelu(as[s] + adn));
            sm += w;
            ushort4 hv = *reinterpret_cast<const ushort4*>(&h3[(size_t)s * 32 + c4]);
            acc.x = fmaf(w, bf2f(hv.x), acc.x);
            acc.y = fmaf(w, bf2f(hv.y), acc.y);
            acc.z = fmaf(w, bf2f(hv.z), acc.z);
            acc.w = fmaf(w, bf2f(hv.w), acc.w);
        }
    }
    #pragma unroll
    for (int off = 8; off < 64; off <<= 1) {
        sm    += __shfl_xor(sm, off);
        acc.x += __shfl_xor(acc.x, off);
        acc.y += __shfl_xor(acc.y, off);
        acc.z += __shfl_xor(acc.z, off);
        acc.w += __shfl_xor(acc.w, off);
    }
    if (e_sub == 0) {
        float il = 1.f / (sm + 1e-16f);
        float4 bv = *reinterpret_cast<const float4*>(&b3[c4]);
        ushort4 xv = *reinterpret_cast<const ushort4*>(&xs[(size_t)n * 32 + c4]);
        float4 o;
        o.x = acc.x * il + bv.x + bf2f(xv.x);
        o.y = acc.y * il + bv.y + bf2f(xv.y);
        o.z = acc.z * il + bv.z + bf2f(xv.z);
        o.w = acc.w * il + bv.w + bf2f(xv.w);
        *reinterpret_cast<float4*>(&out[(size_t)n * 32 + c4]) = o;
    }
}

// ---------------------------------------------------------------- launch
extern "C" void kernel_launch(void* const* d_in, const int* in_sizes, int n_in,
                              void* d_out, int out_size, void* d_ws, size_t ws_size,
                              hipStream_t stream) {
    const float* x      = (const float*)d_in[0];
    const int*   eidx   = (const int*)  d_in[1];
    const float* W1     = (const float*)d_in[2];
    const float* a_src1 = (const float*)d_in[3];
    const float* a_dst1 = (const float*)d_in[4];
    const float* b1     = (const float*)d_in[5];
    const float* bn1_g  = (const float*)d_in[6];
    const float* bn1_b  = (const float*)d_in[7];
    const float* bn1_m  = (const float*)d_in[8];
    const float* bn1_v  = (const float*)d_in[9];
    const float* W2     = (const float*)d_in[10];
    const float* a_src2 = (const float*)d_in[11];
    const float* a_dst2 = (const float*)d_in[12];
    const float* b2     = (const float*)d_in[13];
    const float* bn2_g  = (const float*)d_in[14];
    const float* bn2_b  = (const float*)d_in[15];
    const float* bn2_m  = (const float*)d_in[16];
    const float* bn2_v  = (const float*)d_in[17];
    const float* W3     = (const float*)d_in[18];
    const float* a_src3 = (const float*)d_in[19];
    const float* a_dst3 = (const float*)d_in[20];
    const float* b3     = (const float*)d_in[21];
    const float* Ws1    = (const float*)d_in[22];
    const float* bs1    = (const float*)d_in[23];
    const float* Ws2    = (const float*)d_in[24];
    const float* bs2    = (const float*)d_in[25];

    const int N = in_sizes[0] / 128;   // 50000
    const int E = in_sizes[1] / 2;     // 800000
    const int Etot = E + N;
    const int* srcl = eidx;
    const int* dstl = eidx + E;

    char* ws = (char*)d_ws;
    size_t off = 0;
    auto alloc = [&](size_t bytes) -> void* {
        void* p = ws + off;
        off += (bytes + 255) & ~(size_t)255;
        return p;
    };
    unsigned short* xb    = (unsigned short*)alloc((size_t)N * 128 * 2);
    unsigned short* feat  = (unsigned short*)alloc((size_t)N * 256 * 2); // x0 skip (bf16)
    unsigned short* hbuf  = (unsigned short*)alloc((size_t)N * 256 * 2); // gemm h output
    unsigned short* h2b   = (unsigned short*)alloc((size_t)N * 256 * 2); // layer-1 agg out
    unsigned short* featb = (unsigned short*)alloc((size_t)N * 256 * 2); // layer-2 agg out
    unsigned short* xsbuf = (unsigned short*)alloc((size_t)N * 32 * 2);  // xs skip (bf16)
    unsigned short* h3b   = (unsigned short*)alloc((size_t)N * 32 * 2);
    float*          asb   = (float*)alloc((size_t)N * 8 * 4);
    float*          adb   = (float*)alloc((size_t)N * 8 * 4);
    unsigned short* Wcat1 = (unsigned short*)alloc((size_t)512 * 128 * 2); // [W1t; Ws1t]
    unsigned short* Wcat2 = (unsigned short*)alloc((size_t)288 * 256 * 2); // [W2t; Ws2t]
    unsigned short* W3t   = (unsigned short*)alloc((size_t)32 * 256 * 2);
    int* counts = (int*)alloc((size_t)N * 4);
    int* cursor = (int*)alloc((size_t)N * 4);
    int* indptr = (int*)alloc((size_t)(N + 1) * 4);
    int* bsums  = (int*)alloc(256 * 4);
    int* esrc   = (int*)alloc((size_t)Etot * 4);
    (void)ws_size; (void)n_in; (void)out_size;

    // ---- CSR by dst
    hipMemsetAsync(counts, 0, (size_t)N * 4, stream);
    int ceb = (Etot + 255) / 256;
    int nb  = (N + 255) / 256;
    count_kernel<<<ceb, 256, 0, stream>>>(dstl, E, N, counts);
    scan1<<<nb, 256, 0, stream>>>(counts, cursor, bsums, N);
    scan2<<<1, 256, 0, stream>>>(bsums, nb);
    scan3<<<nb, 256, 0, stream>>>(cursor, bsums, counts, indptr, cursor, N);
    fill_kernel<<<ceb, 256, 0, stream>>>(srcl, dstl, E, N, cursor, esrc);

    // ---- convert inputs (x -> bf16, weights -> transposed bf16) in one dispatch
    int n4x = N * 128 / 4;
    prep_all<<<(n4x + 147456 + 255) / 256, 256, 0, stream>>>(x, xb, n4x,
                                                             W1, Ws1, W2, Ws2, W3,
                                                             Wcat1, Wcat2, W3t);

    int gy128 = (N + 127) / 128;
    int gn4 = (N + 3) / 4;

    // ---- layer 1: fused [h1 | x0] = x @ [W1 | Ws1]
    gemm_tile<<<dim3(4, gy128), 256, 0, stream>>>(xb, Wcat1, hbuf, feat, bs1,
                                                  N, 128, 512, 256, 256, 256);
    alpha256<<<gn4, 256, 0, stream>>>(hbuf, a_src1, a_dst1, asb, adb, N);
    agg256<1><<<gn4, 256, 0, stream>>>(hbuf, asb, adb, indptr, esrc, b1,
                                       bn1_g, bn1_b, bn1_m, bn1_v, feat, h2b, N);

    // ---- layer 2: fused [h2 | xs] = h @ [W2 | Ws2]
    gemm_tile<<<dim3(3, gy128), 256, 0, stream>>>(h2b, Wcat2, hbuf, xsbuf, bs2,
                                                  N, 256, 288, 256, 256, 32);
    alpha256<<<gn4, 256, 0, stream>>>(hbuf, a_src2, a_dst2, asb, adb, N);
    agg256<0><<<gn4, 256, 0, stream>>>(hbuf, asb, adb, indptr, esrc, b2,
                                       bn2_g, bn2_b, bn2_m, bn2_v, nullptr, featb, N);

    // ---- layer 3: tiled GEMM (NCtot=32; staging clamps, epilogue guards)
    gemm_tile<<<dim3(1, gy128), 256, 0, stream>>>(featb, W3t, h3b, h3b, nullptr,
                                                  N, 256, 32, 32, 32, 32);
    alpha32<<<(N + 31) / 32, 256, 0, stream>>>(h3b, a_src3, a_dst3, asb, adb, N);
    agg32<<<gn4, 256, 0, stream>>>(h3b, asb, adb, indptr, esrc, b3, xsbuf,
                                   (float*)d_out, N);
}